// Round 8
// baseline (1636.035 us; speedup 1.0000x reference)
//
#include <hip/hip_runtime.h>
#include <math.h>

// ---------------------------------------------------------------------------
// SENSE CG reconstruction, B=1, S=4, C=16, H=W=320, rho=0.1, 15 CG iters.
// Conjugated by fftshift (even N): CG loop uses plain FFTs; final
// ifft2c(fft2c(x)) == x skipped.
// R6: FFT-320 = Stockham {5,8,8}; stage1 radix-5 in registers; stage3
//     direct to/from global (natural order); inverse = adjoint network.
// R7: all complex math on ext_vector_type(2) -> packed fp32 (v_pk_*).
// R8: TWO independent FFT lines per wave, stage-interleaved (reads of both
//     lines -> one fence -> computes/writes of both). Covers per-wave DS
//     latency with the sibling line's VALU; twiddle chain shared per pair.
//     R7 evidence: pk-fp32 gave only +4% => not VALU-issue-bound; DS
//     dependency-chain latency is the binder (floor calc ~2x slack).
// ---------------------------------------------------------------------------

#define NDIM 320
#define HHALF 160
#define HW (NDIM*NDIM)
#define NS 4
#define NC 16
#define RHO_ 0.1f
#define CG_ITERS 15

typedef float v2f __attribute__((ext_vector_type(2)));

__device__ __forceinline__ void wsync(){
    __builtin_amdgcn_fence(__ATOMIC_ACQ_REL, "wavefront");
    __builtin_amdgcn_wave_barrier();
}

__device__ __forceinline__ float wred(float v){
    #pragma unroll
    for (int o=32;o>0;o>>=1) v += __shfl_down(v,o,64);
    return v;  // valid on lane 0
}

__device__ __forceinline__ v2f cmulf(v2f a, v2f b){
    return (v2f){a.x,a.x}*b + (v2f){-a.y,a.y}*(v2f){b.y,b.x};
}

template<int SIGMA>
__device__ __forceinline__ v2f cmulw(v2f a, v2f w){
    v2f wb = (SIGMA<0) ? w : (v2f){w.x, -w.y};
    return cmulf(a, wb);
}

template<int SIGMA>
__device__ __forceinline__ v2f mulj(v2f z){
    return (v2f){ -(float)SIGMA*z.y, (float)SIGMA*z.x };
}

template<int SIGMA>
__device__ __forceinline__ void radix5(const v2f* u, v2f* v){
    const float C1 = 0.30901699437494742f, S1 = 0.95105651629515357f;
    const float C2 = -0.80901699437494745f, S2 = 0.58778525229247312f;
    v2f t1=u[1]+u[4], t2=u[2]+u[3], t3=u[1]-u[4], t4=u[2]-u[3];
    v[0] = u[0] + t1 + t2;
    v2f m1 = u[0] + t1*C1 + t2*C2;
    v2f m2 = u[0] + t1*C2 + t2*C1;
    v2f n1 = t3*S1 + t4*S2;
    v2f n2 = t3*S2 - t4*S1;
    v2f j1 = mulj<SIGMA>(n1), j2 = mulj<SIGMA>(n2);
    v[1]=m1+j1; v[4]=m1-j1; v[2]=m2+j2; v[3]=m2-j2;
}

template<int SIGMA>
__device__ __forceinline__ void dft8(const v2f* u, v2f* y){
    const float C = 0.70710678118654752f;
    v2f a0=u[0]+u[4], a1=u[0]-u[4];
    v2f a2=u[2]+u[6], a3=u[2]-u[6];
    v2f a4=u[1]+u[5], a5=u[1]-u[5];
    v2f a6=u[3]+u[7], a7=u[3]-u[7];
    v2f j3 = mulj<SIGMA>(a3);
    v2f E0=a0+a2, E2=a0-a2;
    v2f E1=a1+j3, E3=a1-j3;
    v2f j7 = mulj<SIGMA>(a7);
    v2f O0=a4+a6, O2=a4-a6;
    v2f O1=a5+j7, O3=a5-j7;
    v2f W1 = (O1 + mulj<SIGMA>(O1)) * C;
    v2f jO2 = mulj<SIGMA>(O2);
    v2f W3 = (mulj<SIGMA>(O3) - O3) * C;
    y[0]=E0+O0; y[4]=E0-O0;
    y[1]=E1+W1; y[5]=E1-W1;
    y[2]=E2+jO2; y[6]=E2-jO2;
    y[3]=E3+W3; y[7]=E3-W3;
}

// ---- paired (2-line interleaved) forward stages ---------------------------
// S1 writes from regs (no LDS read) -- caller fences before.
template<int SIGMA>
__device__ __forceinline__ void s1_write_pair(v2f* __restrict__ A0,
                                              v2f* __restrict__ A1, int t,
                                              const v2f* u0, const v2f* u1){
    v2f v0[5], v1[5];
    radix5<SIGMA>(u0, v0);
    radix5<SIGMA>(u1, v1);
    #pragma unroll
    for (int c=0;c<5;++c){ A0[5*t+c]=v0[c]; A1[5*t+c]=v1[c]; }
}

template<int SIGMA>
__device__ __forceinline__ void s1_pair(v2f* __restrict__ A0,
                                        v2f* __restrict__ A1, int t){
    v2f u0[5], u1[5];
    #pragma unroll
    for (int q=0;q<5;++q){ u0[q]=A0[t+64*q]; u1[q]=A1[t+64*q]; }
    wsync();
    s1_write_pair<SIGMA>(A0,A1,t,u0,u1);
}

template<int SIGMA>
__device__ __forceinline__ void tw_dft8_pair(v2f* u0, v2f* u1, v2f w,
                                             v2f* v0, v2f* v1){
    v2f wc = w;
    u0[1]=cmulw<SIGMA>(u0[1],wc); u1[1]=cmulw<SIGMA>(u1[1],wc);
    #pragma unroll
    for (int q=2;q<8;++q){
        wc = cmulf(wc, w);
        u0[q]=cmulw<SIGMA>(u0[q],wc); u1[q]=cmulw<SIGMA>(u1[q],wc);
    }
    dft8<SIGMA>(u0, v0);
    dft8<SIGMA>(u1, v1);
}

// S2: P=5. read both, fence, twiddle+dft8+write both.
template<int SIGMA>
__device__ __forceinline__ void s2_pair(v2f* __restrict__ A0,
                                        v2f* __restrict__ A1, int t, v2f w40){
    if (t < 40){
        v2f u0[8], u1[8];
        #pragma unroll
        for (int q=0;q<8;++q){ u0[q]=A0[t+40*q]; u1[q]=A1[t+40*q]; }
        wsync();
        v2f v0[8], v1[8];
        tw_dft8_pair<SIGMA>(u0,u1,w40,v0,v1);
        int k = t % 5, jb = t / 5;
        int base = jb*40 + k;
        #pragma unroll
        for (int c=0;c<8;++c){ A0[base+5*c]=v0[c]; A1[base+5*c]=v1[c]; }
    }
}

// S3: P=40. read both -> regs (v = X[t+40c]); caller consumes/stores.
template<int SIGMA>
__device__ __forceinline__ void s3_pair(const v2f* __restrict__ A0,
                                        const v2f* __restrict__ A1, int t,
                                        v2f w320, v2f* v0, v2f* v1){
    if (t < 40){
        v2f u0[8], u1[8];
        #pragma unroll
        for (int q=0;q<8;++q){ u0[q]=A0[t+40*q]; u1[q]=A1[t+40*q]; }
        tw_dft8_pair<SIGMA>(u0,u1,w320,v0,v1);
    }
}

// ---- paired adjoint (inverse) stages --------------------------------------
template<int SIGMA>
__device__ __forceinline__ void a3_pair(v2f* __restrict__ A0,
                                        v2f* __restrict__ A1, int t,
                                        v2f w320, const v2f* i0, const v2f* i1){
    if (t < 40){
        v2f u0[8], u1[8];
        dft8<SIGMA>(i0, u0);
        dft8<SIGMA>(i1, u1);
        v2f wc = w320;
        u0[1]=cmulw<SIGMA>(u0[1],wc); u1[1]=cmulw<SIGMA>(u1[1],wc);
        #pragma unroll
        for (int q=2;q<8;++q){
            wc = cmulf(wc, w320);
            u0[q]=cmulw<SIGMA>(u0[q],wc); u1[q]=cmulw<SIGMA>(u1[q],wc);
        }
        #pragma unroll
        for (int q=0;q<8;++q){ A0[t+40*q]=u0[q]; A1[t+40*q]=u1[q]; }
    }
}

template<int SIGMA>
__device__ __forceinline__ void a2_pair(v2f* __restrict__ A0,
                                        v2f* __restrict__ A1, int t, v2f w40){
    if (t < 40){
        int k = t % 5, jb = t / 5;
        int base = jb*40 + k;
        v2f v0[8], v1[8];
        #pragma unroll
        for (int c=0;c<8;++c){ v0[c]=A0[base+5*c]; v1[c]=A1[base+5*c]; }
        wsync();
        v2f u0[8], u1[8];
        dft8<SIGMA>(v0, u0);
        dft8<SIGMA>(v1, u1);
        v2f wc = w40;
        u0[1]=cmulw<SIGMA>(u0[1],wc); u1[1]=cmulw<SIGMA>(u1[1],wc);
        #pragma unroll
        for (int q=2;q<8;++q){
            wc = cmulf(wc, w40);
            u0[q]=cmulw<SIGMA>(u0[q],wc); u1[q]=cmulw<SIGMA>(u1[q],wc);
        }
        #pragma unroll
        for (int q=0;q<8;++q){ A0[t+40*q]=u0[q]; A1[t+40*q]=u1[q]; }
    }
}

template<int SIGMA>
__device__ __forceinline__ void a1_pair(const v2f* __restrict__ A0,
                                        const v2f* __restrict__ A1, int t,
                                        v2f* o0, v2f* o1){
    v2f v0[5], v1[5];
    #pragma unroll
    for (int c=0;c<5;++c){ v0[c]=A0[5*t+c]; v1[c]=A1[5*t+c]; }
    radix5<SIGMA>(v0, o0);
    radix5<SIGMA>(v1, o1);
}

__device__ __forceinline__ void make_w(int t, v2f& w40, v2f& w320){
    float sn, cs;
    const float n2pi = -6.283185307179586f;
    __sincosf(n2pi*(float)(t%5)/40.f, &sn, &cs); w40  = (v2f){cs, sn};
    __sincosf(n2pi*(float)t/320.f,    &sn, &cs); w320 = (v2f){cs, sn};
}

__device__ __forceinline__ int sh160(int i){ return i < HHALF ? i + HHALF : i - HHALF; }

// ---------------------------------------------------------------------------
__global__ void k_prep(const v2f* __restrict__ kin, const float* __restrict__ mask,
                       const v2f* __restrict__ csm, v2f* __restrict__ sP,
                       float* __restrict__ mscT, v2f* __restrict__ K,
                       float* __restrict__ scal)
{
    int gid = blockIdx.x*blockDim.x + threadIdx.x;
    int gsz = gridDim.x*blockDim.x;
    if (gid < 64) scal[gid] = 0.f;
    for (int i = gid; i < NC*HW; i += gsz){
        int w = i % NDIM; int h = (i/NDIM) % NDIM; int c = i/HW;
        sP[i] = csm[(c*NDIM + sh160(h))*NDIM + sh160(w)];
    }
    for (int i = gid; i < NS*HW; i += gsz){
        int h = i % NDIM; int wc = (i/NDIM)%NDIM; int s = i/HW;
        float m = mask[(s*NDIM + sh160(h))*NDIM + sh160(wc)];
        mscT[i] = m*m*(1.0f/102400.0f);
    }
    for (int i = gid; i < NS*NC*HW; i += gsz){
        int w = i % NDIM; int h = (i/NDIM)%NDIM; int sc = i/HW;
        int s = sc >> 4;
        int hs = sh160(h), ws = sh160(w);
        float m = mask[(s*NDIM + hs)*NDIM + ws];
        v2f kv = kin[((long)sc*NDIM + hs)*NDIM + ws];
        float f = m*(1.0f/320.0f);
        K[i] = kv * f;
    }
}

// ---------------------------------------------------------------------------
// PassA: p = r + beta*p fused; K[s,c,h,:] = rowFFT(s'_c .* p).
// grid = S*80*4 ; 256 thr = 4 waves, one row per wave, 2 coils per round.
__global__ __launch_bounds__(256) void k_passA(
    const v2f* __restrict__ rv_, const v2f* __restrict__ pOld,
    v2f* __restrict__ pNew, const v2f* __restrict__ sP,
    v2f* __restrict__ K, float* __restrict__ scal, int iter)
{
    int bid = blockIdx.x;
    int cg = bid & 3;
    int hg = (bid>>2) % 80;
    int s  = bid / (4*80);
    int tid = threadIdx.x; int rl = tid>>6; int t = tid&63;
    int h = hg*4 + rl;
    __shared__ v2f buf[8][NDIM];
    v2f* A0 = &buf[2*rl][0];
    v2f* A1 = &buf[2*rl+1][0];
    v2f w40, w320; make_w(t, w40, w320);
    float beta = 0.f;
    if (iter > 0) beta = scal[iter] / (scal[iter-1] + 1e-12f);
    long base = (long)s*HW + h*NDIM;
    v2f pv[5];
    #pragma unroll
    for (int j=0;j<5;++j){
        int idx = t + 64*j;
        v2f rr = rv_[base+idx];
        if (iter > 0){
            v2f pp = pOld[base+idx];
            pv[j] = rr + pp*beta;
        } else pv[j] = rr;
    }
    if (cg == 0){
        float d = 0.f;
        #pragma unroll
        for (int j=0;j<5;++j){
            pNew[base + t + 64*j] = pv[j];
            d += pv[j].x*pv[j].x + pv[j].y*pv[j].y;
        }
        float wd = wred(d);
        if (t==0) atomicAdd(&scal[16+iter], RHO_*wd);
    }
    int c = cg*4;
    const v2f* srow = sP + (long)c*HW + h*NDIM;
    v2f sv0[5], sv1[5];
    #pragma unroll
    for (int j=0;j<5;++j){ sv0[j] = srow[t+64*j]; sv1[j] = srow[HW + t+64*j]; }
    #pragma unroll
    for (int pair=0;pair<2;++pair){
        v2f u0[5], u1[5];
        #pragma unroll
        for (int j=0;j<5;++j){ u0[j]=cmulf(sv0[j],pv[j]); u1[j]=cmulf(sv1[j],pv[j]); }
        v2f sn0[5], sn1[5];
        if (pair==0){
            const v2f* sr2 = srow + (long)2*HW;
            #pragma unroll
            for (int j=0;j<5;++j){ sn0[j]=sr2[t+64*j]; sn1[j]=sr2[HW + t+64*j]; }
        }
        wsync();                        // prior pair's S3 LDS reads complete
        s1_write_pair<-1>(A0,A1,t,u0,u1);
        wsync();
        s2_pair<-1>(A0,A1,t,w40);
        wsync();
        v2f v0[8], v1[8];
        s3_pair<-1>(A0,A1,t,w320,v0,v1);
        long kb = ((long)(s*NC + c + 2*pair))*HW + h*NDIM;
        if (t < 40){
            #pragma unroll
            for (int cc=0;cc<8;++cc){
                K[kb + t + 40*cc]      = v0[cc];
                K[kb + HW + t + 40*cc] = v1[cc];
            }
        }
        if (pair==0){
            #pragma unroll
            for (int j=0;j<5;++j){ sv0[j]=sn0[j]; sv1[j]=sn1[j]; }
        }
    }
}

// ---------------------------------------------------------------------------
// PassB: per (s,c) image, 8-column LDS tile; 256 thr = 4 waves, 2 columns
// per wave. colFFT -> mask*scale -> colIFFT(adjoint) (doMask=1) or colIFFT
// only (doMask=0, sigma=+1 forward network). In-place on K. LDS 20.7KB.
__global__ __launch_bounds__(256) void k_passB(v2f* __restrict__ K,
    const float* __restrict__ mscT, int doMask)
{
    constexpr int L = 324;
    int bid = blockIdx.x;
    int wt = bid % 40;
    int sc = bid / 40;
    int s = sc >> 4;
    int tid = threadIdx.x;
    int col = tid >> 6;          // wave id 0..3
    int t = tid & 63;
    int w0 = wt*8;
    __shared__ v2f buf[8][L];
    v2f* A0 = &buf[2*col][0];
    v2f* A1 = &buf[2*col+1][0];
    v2f w40, w320; make_w(t, w40, w320);
    float mv0[8], mv1[8];
    if (doMask && t < 40){
        const float* mcol = mscT + (long)s*HW + (long)(w0+2*col)*NDIM;
        #pragma unroll
        for (int cc=0;cc<8;++cc){ mv0[cc]=mcol[t+40*cc]; mv1[cc]=mcol[NDIM + t+40*cc]; }
    }
    long gb = (long)sc*HW;
    int wl = tid & 7, hb = tid >> 3;  // 64B contiguous per 8 lanes, 32 rows/sweep
    #pragma unroll
    for (int j=0;j<10;++j){
        int hh = hb + 32*j;
        buf[wl][hh] = K[gb + (long)hh*NDIM + w0 + wl];
    }
    __syncthreads();
    if (doMask){
        s1_pair<-1>(A0,A1,t);
        wsync();
        s2_pair<-1>(A0,A1,t,w40);
        wsync();
        v2f v0[8], v1[8];
        s3_pair<-1>(A0,A1,t,w320,v0,v1);
        if (t < 40){
            #pragma unroll
            for (int cc=0;cc<8;++cc){ v0[cc]=v0[cc]*mv0[cc]; v1[cc]=v1[cc]*mv1[cc]; }
        }
        wsync();
        a3_pair<1>(A0,A1,t,w320,v0,v1);
        wsync();
        a2_pair<1>(A0,A1,t,w40);
        wsync();
        v2f x0[5], x1[5];
        a1_pair<1>(A0,A1,t,x0,x1);
        wsync();
        #pragma unroll
        for (int q=0;q<5;++q){ A0[t+64*q]=x0[q]; A1[t+64*q]=x1[q]; }
    } else {
        s1_pair<1>(A0,A1,t);
        wsync();
        s2_pair<1>(A0,A1,t,w40);
        wsync();
        v2f v0[8], v1[8];
        s3_pair<1>(A0,A1,t,w320,v0,v1);
        wsync();
        if (t < 40){
            #pragma unroll
            for (int cc=0;cc<8;++cc){ A0[t+40*cc]=v0[cc]; A1[t+40*cc]=v1[cc]; }
        }
    }
    __syncthreads();
    #pragma unroll
    for (int j=0;j<10;++j){
        int hh = hb + 32*j;
        K[gb + (long)hh*NDIM + w0 + wl] = buf[wl][hh];
    }
}

// ---------------------------------------------------------------------------
// PassC2: row inverse (adjoint network) of one coil-group (4 coils, 2 per
// round), conj(s')-combine into part[cg]; optional partial p.part dot.
__global__ __launch_bounds__(256) void k_passC2(
    const v2f* __restrict__ K, const v2f* __restrict__ sP,
    const v2f* __restrict__ pVec, v2f* __restrict__ part,
    float* __restrict__ scal, int dotSlot, int doDot)
{
    int bid = blockIdx.x;
    int cg = bid & 3;
    int hg = (bid>>2) % 80;
    int s  = bid / (4*80);
    int tid = threadIdx.x; int rl = tid>>6; int t = tid&63;
    int h = hg*4 + rl;
    __shared__ v2f buf[8][NDIM];
    __shared__ float redS[4];
    v2f* A0 = &buf[2*rl][0];
    v2f* A1 = &buf[2*rl+1][0];
    v2f w40, w320; make_w(t, w40, w320);
    int c = cg*4;
    long kb0 = ((long)(s*NC + c))*HW + h*NDIM;
    const v2f* srow = sP + (long)c*HW + h*NDIM;
    v2f kv0[8], kv1[8], sv0[5], sv1[5];
    if (t < 40){
        #pragma unroll
        for (int cc=0;cc<8;++cc){ kv0[cc]=K[kb0 + t+40*cc]; kv1[cc]=K[kb0 + HW + t+40*cc]; }
    }
    #pragma unroll
    for (int j=0;j<5;++j){ sv0[j]=srow[t+64*j]; sv1[j]=srow[HW + t+64*j]; }
    v2f acc[5];
    #pragma unroll
    for (int j=0;j<5;++j) acc[j]=(v2f){0.f,0.f};
    #pragma unroll
    for (int pair=0;pair<2;++pair){
        a3_pair<1>(A0,A1,t,w320,kv0,kv1);
        v2f kn0[8], kn1[8], sn0[5], sn1[5];
        if (pair==0){
            long kb = kb0 + (long)2*HW;
            const v2f* sr2 = srow + (long)2*HW;
            if (t < 40){
                #pragma unroll
                for (int cc=0;cc<8;++cc){ kn0[cc]=K[kb + t+40*cc]; kn1[cc]=K[kb + HW + t+40*cc]; }
            }
            #pragma unroll
            for (int j=0;j<5;++j){ sn0[j]=sr2[t+64*j]; sn1[j]=sr2[HW + t+64*j]; }
        }
        wsync();
        a2_pair<1>(A0,A1,t,w40);
        wsync();
        v2f x0[5], x1[5];
        a1_pair<1>(A0,A1,t,x0,x1);
        #pragma unroll
        for (int j=0;j<5;++j){
            acc[j] += (v2f){sv0[j].x,sv0[j].x}*x0[j]
                    + (v2f){sv0[j].y,-sv0[j].y}*(v2f){x0[j].y,x0[j].x};
            acc[j] += (v2f){sv1[j].x,sv1[j].x}*x1[j]
                    + (v2f){sv1[j].y,-sv1[j].y}*(v2f){x1[j].y,x1[j].x};
        }
        wsync();                   // a1 reads done before next a3 writes
        if (pair==0){
            #pragma unroll
            for (int cc=0;cc<8;++cc){ kv0[cc]=kn0[cc]; kv1[cc]=kn1[cc]; }
            #pragma unroll
            for (int j=0;j<5;++j){ sv0[j]=sn0[j]; sv1[j]=sn1[j]; }
        }
    }
    long pbase = (long)s*HW + h*NDIM;
    long obase = ((long)cg*NS + s)*HW + h*NDIM;
    float dot = 0.f;
    #pragma unroll
    for (int j=0;j<5;++j){
        int idx=t+64*j;
        part[obase+idx] = acc[j];
        if (doDot){
            v2f pp = pVec[pbase+idx];
            dot += pp.x*acc[j].x + pp.y*acc[j].y;
        }
    }
    if (doDot){
        float wd = wred(dot);
        if (t==0) redS[rl] = wd;
        __syncthreads();
        if (tid==0) atomicAdd(&scal[dotSlot], redS[0]+redS[1]+redS[2]+redS[3]);
    }
}

// ---------------------------------------------------------------------------
__global__ __launch_bounds__(256) void k_rhs_fin(
    const v2f* __restrict__ part, const v2f* __restrict__ Iin,
    v2f* __restrict__ r, v2f* __restrict__ x, float* __restrict__ scal)
{
    __shared__ float red[256];
    int gid = blockIdx.x*blockDim.x + threadIdx.x;
    int gsz = gridDim.x*blockDim.x;
    float rs = 0.f;
    const int NV = NS*HW;
    for (int i = gid; i < NV; i += gsz){
        int w = i % NDIM; int h = (i/NDIM)%NDIM; int s = i/HW;
        v2f iv = Iin[((long)s*NDIM + sh160(h))*NDIM + sh160(w)];
        v2f rr = part[i] + part[NV+i] + part[2*NV+i] + part[3*NV+i] + iv*RHO_;
        r[i] = rr;
        x[i] = (v2f){0.f,0.f};
        rs += rr.x*rr.x + rr.y*rr.y;
    }
    red[threadIdx.x]=rs; __syncthreads();
    for (int o=128;o>0;o>>=1){ if (threadIdx.x<o) red[threadIdx.x]+=red[threadIdx.x+o]; __syncthreads(); }
    if (threadIdx.x==0) atomicAdd(&scal[0], red[0]);
}

// ---------------------------------------------------------------------------
__global__ __launch_bounds__(256) void k_update(
    v2f* __restrict__ x, v2f* __restrict__ r,
    const v2f* __restrict__ p, const v2f* __restrict__ part,
    float* __restrict__ scal, int iter)
{
    __shared__ float red[256];
    float alpha = scal[iter] / (scal[16+iter] + 1e-12f);
    int gid = blockIdx.x*blockDim.x + threadIdx.x;
    int gsz = gridDim.x*blockDim.x;
    float rs = 0.f;
    const int NV = NS*HW;
    for (int i = gid; i < NV; i += gsz){
        v2f pvv=p[i];
        v2f av = part[i] + part[NV+i] + part[2*NV+i] + part[3*NV+i] + pvv*RHO_;
        v2f xv = x[i] + pvv*alpha;
        v2f rv = r[i] - av*alpha;
        x[i]=xv; r[i]=rv;
        rs += rv.x*rv.x + rv.y*rv.y;
    }
    red[threadIdx.x]=rs; __syncthreads();
    for (int o=128;o>0;o>>=1){ if (threadIdx.x<o) red[threadIdx.x]+=red[threadIdx.x+o]; __syncthreads(); }
    if (threadIdx.x==0) atomicAdd(&scal[iter+1], red[0]);
}

__global__ void k_final(const v2f* __restrict__ x, v2f* __restrict__ out)
{
    int gid = blockIdx.x*blockDim.x + threadIdx.x;
    int gsz = gridDim.x*blockDim.x;
    for (int i = gid; i < NS*HW; i += gsz){
        int w = i % NDIM; int h = (i/NDIM)%NDIM; int s = i/HW;
        out[i] = x[(long)s*HW + sh160(h)*NDIM + sh160(w)];
    }
}

extern "C" void kernel_launch(void* const* d_in, const int* in_sizes, int n_in,
                              void* d_out, int out_size, void* d_ws, size_t ws_size,
                              hipStream_t stream) {
    (void)in_sizes; (void)n_in; (void)out_size; (void)ws_size;
    const v2f* kin  = (const v2f*)d_in[0];
    const v2f* Iin  = (const v2f*)d_in[1];
    const v2f* csm  = (const v2f*)d_in[2];
    const float* mask = (const float*)d_in[3];

    char* w = (char*)d_ws;
    size_t off = 0;
    float* scal = (float*)(w+off);  off += 1024;
    v2f* sP   = (v2f*)(w+off); off += (size_t)NC*HW*8;
    float* mscT = (float*)(w+off); off += (size_t)NS*HW*4;
    v2f* K    = (v2f*)(w+off); off += (size_t)NS*NC*HW*8;
    v2f* x    = (v2f*)(w+off); off += (size_t)NS*HW*8;
    v2f* r    = (v2f*)(w+off); off += (size_t)NS*HW*8;
    v2f* pA   = (v2f*)(w+off); off += (size_t)NS*HW*8;
    v2f* pB   = (v2f*)(w+off); off += (size_t)NS*HW*8;
    v2f* part = (v2f*)(w+off); off += (size_t)4*NS*HW*8;

    k_prep<<<2048,256,0,stream>>>(kin, mask, csm, sP, mscT, K, scal);
    k_passB<<<NS*NC*40,256,0,stream>>>(K, mscT, 0);
    k_passC2<<<NS*80*4,256,0,stream>>>(K, sP, r, part, scal, 63, 0);
    k_rhs_fin<<<640,256,0,stream>>>(part, Iin, r, x, scal);

    for (int it=0; it<CG_ITERS; ++it){
        v2f* pNew = (it&1)? pB : pA;
        v2f* pOld = (it&1)? pA : pB;
        k_passA<<<NS*80*4,256,0,stream>>>(r, pOld, pNew, sP, K, scal, it);
        k_passB<<<NS*NC*40,256,0,stream>>>(K, mscT, 1);
        k_passC2<<<NS*80*4,256,0,stream>>>(K, sP, pNew, part, scal, 16+it, 1);
        k_update<<<640,256,0,stream>>>(x, r, pNew, part, scal, it);
    }
    k_final<<<512,256,0,stream>>>(x, (v2f*)d_out);
}